// Round 7
// baseline (158.896 us; speedup 1.0000x reference)
//
#include <hip/hip_runtime.h>

#define NWIN 4096
#define DIM 96
#define HEADS 6
#define NTOK 64

typedef __bf16 bf16x8 __attribute__((ext_vector_type(8)));
typedef __bf16 bf16x4 __attribute__((ext_vector_type(4)));
typedef short  s16x4  __attribute__((ext_vector_type(4)));
typedef float  f32x4  __attribute__((ext_vector_type(4)));

// d_ws layout
#define WS_QKVW 0                   // 288*96 bf16 = 55296 B
#define WS_PROJW 55296              // 96*96 bf16  = 18432 B
#define WS_BIAS 73728               // 6*16*64 float4 = 98304 B (frag-ordered)
#define WS_TOTAL 172032

__device__ __forceinline__ f32x4 mfma32(bf16x8 a, bf16x8 b, f32x4 c) {
  return __builtin_amdgcn_mfma_f32_16x16x32_bf16(a, b, c, 0, 0, 0);
}
// K=16 MFMA: A/B fragment lane(l16,lq) holds row=l16, k=4*lq+e — identical
// to the W*X^T D-fragment (row=4lq+r, col=l16), so K and Q never touch LDS.
__device__ __forceinline__ f32x4 mfma16k(bf16x4 a, bf16x4 b, f32x4 c) {
  return __builtin_amdgcn_mfma_f32_16x16x16bf16_1k(
      __builtin_bit_cast(s16x4, a), __builtin_bit_cast(s16x4, b), c, 0, 0, 0);
}

__device__ __forceinline__ bf16x8 cvt8(const float* p) {
  const float4* q = (const float4*)p;
  float4 a = q[0];
  float4 b = q[1];
  bf16x8 r;
  r[0] = (__bf16)a.x; r[1] = (__bf16)a.y; r[2] = (__bf16)a.z; r[3] = (__bf16)a.w;
  r[4] = (__bf16)b.x; r[5] = (__bf16)b.y; r[6] = (__bf16)b.z; r[7] = (__bf16)b.w;
  return r;
}

// Pre-pass: weights -> bf16; bias gathered into MFMA-fragment order:
// bias[((h*16 + bq*4 + a)*64 + lane)*4 + r] = rpb[rpi[qrow*64+kcol]*6+h]
// with qrow = 16*bq + (lane&15), kcol = 16*a + 4*(lane>>4) + r.
__global__ void prep_kernel(const float* __restrict__ qkv_w,
                            const float* __restrict__ proj_w,
                            const float* __restrict__ rpb,
                            const int* __restrict__ rpi,
                            char* __restrict__ ws) {
  int i = blockIdx.x * blockDim.x + threadIdx.x;
  __bf16* qw = (__bf16*)(ws + WS_QKVW);
  __bf16* pw = (__bf16*)(ws + WS_PROJW);
  float* bias = (float*)(ws + WS_BIAS);
  if (i < 288 * 96) qw[i] = (__bf16)qkv_w[i];
  int j = i - 288 * 96;
  if (j >= 0 && j < 96 * 96) pw[j] = (__bf16)proj_w[j];
  int t = i - (288 * 96 + 96 * 96);
  if (t >= 0 && t < HEADS * 16 * 64 * 4) {
    int r = t & 3;
    int lane = (t >> 2) & 63;
    int ba = (t >> 8) & 15;
    int h = t >> 12;
    int bq = ba >> 2, a = ba & 3;
    int l16 = lane & 15, lq = lane >> 4;
    int qrow = 16 * bq + l16;
    int kcol = 16 * a + 4 * lq + r;
    bias[t] = rpb[rpi[qrow * 64 + kcol] * HEADS + h];
  }
}

// One block = one window; 6 waves, wave w owns head w until proj.
// LDS: region0 = xfrag 12288 B (x fragments; ao[64][104]=13312 B overlays it
// post-barrier) + per-head vT[16][72] 2304 B (Pt 1024 bf16 = 2048 B overlays
// it after vbf hoist). Total 13312 + 6*2304 = 27136 B -> 5 blocks/CU.
// NOTE: gfx950 occupancy tiers are coarse (waves/SIMD halve at VGPR 64/128),
// so any min-waves in (4,8] means an effective 64-VGPR cap -> keep live set
// lean (bf16x4 K/Q frags via mfma16k) and pin the 8-wave tier explicitly.
template <bool USE_WS>
__global__ __launch_bounds__(384, 8) void win_attn(
    const float* __restrict__ x,
    const int* __restrict__ rpi,
    const float* __restrict__ qkv_w,
    const float* __restrict__ qkv_b,
    const float* __restrict__ proj_w,
    const float* __restrict__ proj_b,
    const float* __restrict__ rpb,
    const char* __restrict__ ws,
    float* __restrict__ out) {
  __shared__ __align__(16) __bf16 lds[6656 + HEADS * 1152];

  const int tid = (int)threadIdx.x;
  const int wv = tid >> 6;
  const int lane = tid & 63;
  const int l16 = lane & 15;
  const int lq = lane >> 4;
  const int b = (int)blockIdx.x;

  __bf16* xfrag = lds;                 // 12 frags * 512 bf16 = 12288 B
  __bf16* ao = lds;                    // [64][104] overlay (post-barrier)
  __bf16* vh = lds + 6656 + wv * 1152; // vT[16][72]
  __bf16* Pt = vh;                     // 1024 bf16 overlay (post vbf hoist)

  const float* xw = x + (size_t)b * (NTOK * DIM);
  const __bf16* qwb = (const __bf16*)(ws + WS_QKVW);
  const __bf16* pwb = (const __bf16*)(ws + WS_PROJW);
  const float4* bias4 = (const float4*)(ws + WS_BIAS) + (wv << 10);

  // ---- stage x fragments once per block (wave wv does frags 2wv, 2wv+1) ----
#pragma unroll
  for (int ff = 0; ff < 2; ++ff) {
    const int f = 2 * wv + ff;
    const int mt = f / 3, ks = f - 3 * mt;
    bf16x8 v = cvt8(xw + (16 * mt + l16) * DIM + 32 * ks + 8 * lq);
    *(bf16x8*)(xfrag + (f * 64 + lane) * 8) = v;
  }
  __syncthreads();

#define XV(mt, ks) (*(const bf16x8*)(xfrag + (((mt) * 3 + (ks)) * 64 + lane) * 8))

  // ---- K phase: D = Wk * X^T; D-frag (feat=4lq+r, tok=l16) stays in regs ----
  bf16x4 kb[4];
  {
    const int frow = (HEADS + wv) * 16;
    bf16x8 wb[3];
#pragma unroll
    for (int ks = 0; ks < 3; ++ks) {
      if constexpr (USE_WS)
        wb[ks] = *(const bf16x8*)(qwb + (frow + l16) * 96 + 32 * ks + 8 * lq);
      else
        wb[ks] = cvt8(qkv_w + (frow + l16) * 96 + 32 * ks + 8 * lq);
    }
    const float4 kb4 = *(const float4*)(qkv_b + frow + 4 * lq);
    const float kbv[4] = {kb4.x, kb4.y, kb4.z, kb4.w};
#pragma unroll
    for (int mt = 0; mt < 4; ++mt) {
      f32x4 acc = {0.f, 0.f, 0.f, 0.f};
#pragma unroll
      for (int ks = 0; ks < 3; ++ks) acc = mfma32(wb[ks], XV(mt, ks), acc);
#pragma unroll
      for (int r = 0; r < 4; ++r) kb[mt][r] = (__bf16)(acc[r] + kbv[r]);
    }
  }

  // ---- Q phase: D = Wq * X^T (scaled); registers only ----
  bf16x4 qv4[4];
  {
    const int frow = wv * 16;
    bf16x8 wb[3];
#pragma unroll
    for (int ks = 0; ks < 3; ++ks) {
      if constexpr (USE_WS)
        wb[ks] = *(const bf16x8*)(qwb + (frow + l16) * 96 + 32 * ks + 8 * lq);
      else
        wb[ks] = cvt8(qkv_w + (frow + l16) * 96 + 32 * ks + 8 * lq);
    }
    const float4 qb4 = *(const float4*)(qkv_b + frow + 4 * lq);
    const float qbv[4] = {qb4.x, qb4.y, qb4.z, qb4.w};
#pragma unroll
    for (int mt = 0; mt < 4; ++mt) {
      f32x4 acc = {0.f, 0.f, 0.f, 0.f};
#pragma unroll
      for (int ks = 0; ks < 3; ++ks) acc = mfma32(wb[ks], XV(mt, ks), acc);
#pragma unroll
      for (int r = 0; r < 4; ++r) qv4[mt][r] = (__bf16)((acc[r] + qbv[r]) * 0.25f);
    }
  }

  // ---- V phase: D = X * Wv^T -> vT[feature][token] in LDS ----
  {
    const int frow = (2 * HEADS + wv) * 16;
    bf16x8 wb[3];
#pragma unroll
    for (int ks = 0; ks < 3; ++ks) {
      if constexpr (USE_WS)
        wb[ks] = *(const bf16x8*)(qwb + (frow + l16) * 96 + 32 * ks + 8 * lq);
      else
        wb[ks] = cvt8(qkv_w + (frow + l16) * 96 + 32 * ks + 8 * lq);
    }
    const float vb = qkv_b[frow + l16];
#pragma unroll
    for (int mt = 0; mt < 4; ++mt) {
      f32x4 acc = {0.f, 0.f, 0.f, 0.f};
#pragma unroll
      for (int ks = 0; ks < 3; ++ks) acc = mfma32(XV(mt, ks), wb[ks], acc);
      bf16x4 t;
#pragma unroll
      for (int r = 0; r < 4; ++r) t[r] = (__bf16)(acc[r] + vb);
      *(bf16x4*)(vh + l16 * 72 + 16 * mt + 4 * lq) = t;
    }
  }
  asm volatile("s_waitcnt lgkmcnt(0)" ::: "memory");  // vT visible to all lanes
  bf16x8 vbf[2];
#pragma unroll
  for (int c = 0; c < 2; ++c)
    vbf[c] = *(const bf16x8*)(vh + l16 * 72 + 32 * c + 8 * lq);

  // all waves done with xfrag; vbf reads drained by the barrier's fence
  __syncthreads();

  // ---- attention per q-tile: S^T = K*Q^T (K=16 mfma), bias C-init ----
  // P[q=l16][k] at byte (k>>3)*256 + l16*16 + (k&7)*2  (bijective, 2048 B).
#pragma unroll
  for (int bq = 0; bq < 4; ++bq) {
    f32x4 s[4];
    if constexpr (USE_WS) {
#pragma unroll
      for (int a = 0; a < 4; ++a) {
        float4 t = bias4[(bq * 4 + a) * 64 + lane];
        s[a][0] = t.x; s[a][1] = t.y; s[a][2] = t.z; s[a][3] = t.w;
      }
    } else {
#pragma unroll
      for (int a = 0; a < 4; ++a)
#pragma unroll
        for (int r = 0; r < 4; ++r)
          s[a][r] = rpb[rpi[(16 * bq + l16) * 64 + 16 * a + 4 * lq + r] * HEADS + wv];
    }

#pragma unroll
    for (int a = 0; a < 4; ++a) s[a] = mfma16k(kb[a], qv4[bq], s[a]);

    // logits tiny (|s| << 1): exp directly, no max subtraction
    float tp[4];
#pragma unroll
    for (int a = 0; a < 4; ++a) {
      float t0 = 0.f;
#pragma unroll
      for (int r = 0; r < 4; ++r) {
        float e = __expf(s[a][r]);
        s[a][r] = e;
        t0 += e;
      }
      tp[a] = t0;
    }
    float tsum = (tp[0] + tp[1]) + (tp[2] + tp[3]);
    tsum += __shfl_xor(tsum, 16);
    tsum += __shfl_xor(tsum, 32);
    const float rv = 1.0f / tsum;

    // P -> Pt: writer (k=16a+4lq+r) -> bf16 off (2a+(lq>>1))*128+l16*8+(lq&1)*4
#pragma unroll
    for (int a = 0; a < 4; ++a) {
      bf16x4 p;
#pragma unroll
      for (int r = 0; r < 4; ++r) p[r] = (__bf16)(s[a][r] * rv);
      *(bf16x4*)(Pt + (2 * a + (lq >> 1)) * 128 + l16 * 8 + (lq & 1) * 4) = p;
    }
    asm volatile("s_waitcnt lgkmcnt(0)" ::: "memory");

    f32x4 oacc = {0.f, 0.f, 0.f, 0.f};
#pragma unroll
    for (int c = 0; c < 2; ++c) {
      // reader (k=32c+8lq+e) -> bf16 off c*512 + lane*8, linear b128
      const bf16x8 pa = *(const bf16x8*)(Pt + c * 512 + lane * 8);
      oacc = mfma32(pa, vbf[c], oacc);
    }
    asm volatile("s_waitcnt lgkmcnt(0)" ::: "memory");  // drain before overwrite

    // stage this tile's attn-out (ao region valid post-barrier)
#pragma unroll
    for (int r = 0; r < 4; ++r)
      ao[(16 * bq + 4 * lq + r) * 104 + 16 * wv + l16] = (__bf16)oacc[r];
  }
  __syncthreads();

  // ---- proj ----
  bf16x8 wpb[3];
#pragma unroll
  for (int ks = 0; ks < 3; ++ks) {
    if constexpr (USE_WS)
      wpb[ks] = *(const bf16x8*)(pwb + (16 * wv + l16) * 96 + 32 * ks + 8 * lq);
    else
      wpb[ks] = cvt8(proj_w + (16 * wv + l16) * 96 + 32 * ks + 8 * lq);
  }
  const float pb2 = proj_b[16 * wv + l16];
  float* outw = out + (size_t)b * (NTOK * DIM);
#pragma unroll
  for (int mt = 0; mt < 4; ++mt) {
    f32x4 acc = {0.f, 0.f, 0.f, 0.f};
#pragma unroll
    for (int ks = 0; ks < 3; ++ks) {
      bf16x8 aa = *(const bf16x8*)(ao + (16 * mt + l16) * 104 + 32 * ks + 8 * lq);
      acc = mfma32(aa, wpb[ks], acc);
    }
#pragma unroll
    for (int r = 0; r < 4; ++r)
      outw[(16 * mt + 4 * lq + r) * 96 + 16 * wv + l16] = acc[r] + pb2;
  }
}

extern "C" void kernel_launch(void* const* d_in, const int* in_sizes, int n_in,
                              void* d_out, int out_size, void* d_ws, size_t ws_size,
                              hipStream_t stream) {
  const float* x      = (const float*)d_in[0];
  const int*   rpi    = (const int*)d_in[1];
  const float* qkv_w  = (const float*)d_in[2];
  const float* qkv_b  = (const float*)d_in[3];
  const float* proj_w = (const float*)d_in[4];
  const float* proj_b = (const float*)d_in[5];
  const float* rpb    = (const float*)d_in[6];
  float* out = (float*)d_out;

  if (ws_size >= (size_t)WS_TOTAL) {
    prep_kernel<<<240, 256, 0, stream>>>(qkv_w, proj_w, rpb, rpi, (char*)d_ws);
    win_attn<true><<<NWIN, 384, 0, stream>>>(x, rpi, qkv_w, qkv_b, proj_w,
                                             proj_b, rpb, (const char*)d_ws, out);
  } else {
    win_attn<false><<<NWIN, 384, 0, stream>>>(x, rpi, qkv_w, qkv_b, proj_w,
                                              proj_b, rpb, (const char*)d_ws, out);
  }
}

// Round 8
// 82.008 us; speedup vs baseline: 1.9376x; 1.9376x over previous
//
#include <hip/hip_runtime.h>

#define NWIN 4096
#define DIM 96
#define HEADS 6
#define NTOK 64

typedef __bf16 bf16x8 __attribute__((ext_vector_type(8)));
typedef __bf16 bf16x4 __attribute__((ext_vector_type(4)));
typedef short  s16x4  __attribute__((ext_vector_type(4)));
typedef float  f32x4  __attribute__((ext_vector_type(4)));

// d_ws layout
#define WS_QKVW 0                   // 288*96 bf16 = 55296 B
#define WS_PROJW 55296              // 96*96 bf16  = 18432 B
#define WS_BIAS 73728               // 6*16*64 float4 = 98304 B (frag-ordered)
#define WS_TOTAL 172032

__device__ __forceinline__ f32x4 mfma32(bf16x8 a, bf16x8 b, f32x4 c) {
  return __builtin_amdgcn_mfma_f32_16x16x32_bf16(a, b, c, 0, 0, 0);
}
// K=16 MFMA: A/B fragment lane(l16,lq) holds row=l16, k=4*lq+e — identical
// to the W*X^T D-fragment (row=4lq+r, col=l16), so K and Q never touch LDS.
__device__ __forceinline__ f32x4 mfma16k(bf16x4 a, bf16x4 b, f32x4 c) {
  return __builtin_amdgcn_mfma_f32_16x16x16bf16_1k(
      __builtin_bit_cast(s16x4, a), __builtin_bit_cast(s16x4, b), c, 0, 0, 0);
}

__device__ __forceinline__ bf16x8 cvt8(const float* p) {
  const float4* q = (const float4*)p;
  float4 a = q[0];
  float4 b = q[1];
  bf16x8 r;
  r[0] = (__bf16)a.x; r[1] = (__bf16)a.y; r[2] = (__bf16)a.z; r[3] = (__bf16)a.w;
  r[4] = (__bf16)b.x; r[5] = (__bf16)b.y; r[6] = (__bf16)b.z; r[7] = (__bf16)b.w;
  return r;
}

// Pre-pass: weights -> bf16; bias gathered into MFMA-fragment order:
// bias[((h*16 + bq*4 + a)*64 + lane)*4 + r] = rpb[rpi[qrow*64+kcol]*6+h]
// with qrow = 16*bq + (lane&15), kcol = 16*a + 4*(lane>>4) + r.
__global__ void prep_kernel(const float* __restrict__ qkv_w,
                            const float* __restrict__ proj_w,
                            const float* __restrict__ rpb,
                            const int* __restrict__ rpi,
                            char* __restrict__ ws) {
  int i = blockIdx.x * blockDim.x + threadIdx.x;
  __bf16* qw = (__bf16*)(ws + WS_QKVW);
  __bf16* pw = (__bf16*)(ws + WS_PROJW);
  float* bias = (float*)(ws + WS_BIAS);
  if (i < 288 * 96) qw[i] = (__bf16)qkv_w[i];
  int j = i - 288 * 96;
  if (j >= 0 && j < 96 * 96) pw[j] = (__bf16)proj_w[j];
  int t = i - (288 * 96 + 96 * 96);
  if (t >= 0 && t < HEADS * 16 * 64 * 4) {
    int r = t & 3;
    int lane = (t >> 2) & 63;
    int ba = (t >> 8) & 15;
    int h = t >> 12;
    int bq = ba >> 2, a = ba & 3;
    int l16 = lane & 15, lq = lane >> 4;
    int qrow = 16 * bq + l16;
    int kcol = 16 * a + 4 * lq + r;
    bias[t] = rpb[rpi[qrow * 64 + kcol] * HEADS + h];
  }
}

// One block = one window; 6 waves, wave w owns head w until proj.
// LDS: region0 = xfrag 12288 B (x fragments; ao[64][104]=13312 B overlays it
// post-barrier) + per-head vT[16][72] 2304 B (Pt 1024 bf16 = 2048 B overlays
// it after vbf hoist). Total 13312 + 6*2304 = 27136 B.
// LAUNCH BOUNDS LESSON (r3/r6/r7): min-waves w sets a HARD unified VGPR+AGPR
// budget of 512/w. w=8 -> 64 budget vs ~75 live set -> ~490 MB/dispatch of
// scratch spill (r7: FETCH 190/WRITE 392 MB, dur 159us). Use w=4 (budget 128):
// allocator lands ~75-90 naturally -> floor(512/vgpr)>=6 waves/SIMD anyway,
// with ZERO spill. Never pin occupancy the allocator can't afford.
template <bool USE_WS>
__global__ __launch_bounds__(384, 4) void win_attn(
    const float* __restrict__ x,
    const int* __restrict__ rpi,
    const float* __restrict__ qkv_w,
    const float* __restrict__ qkv_b,
    const float* __restrict__ proj_w,
    const float* __restrict__ proj_b,
    const float* __restrict__ rpb,
    const char* __restrict__ ws,
    float* __restrict__ out) {
  __shared__ __align__(16) __bf16 lds[6656 + HEADS * 1152];

  const int tid = (int)threadIdx.x;
  const int wv = tid >> 6;
  const int lane = tid & 63;
  const int l16 = lane & 15;
  const int lq = lane >> 4;
  const int b = (int)blockIdx.x;

  __bf16* xfrag = lds;                 // 12 frags * 512 bf16 = 12288 B
  __bf16* ao = lds;                    // [64][104] overlay (post-barrier)
  __bf16* vh = lds + 6656 + wv * 1152; // vT[16][72]
  __bf16* Pt = vh;                     // 1024 bf16 overlay (post vbf hoist)

  const float* xw = x + (size_t)b * (NTOK * DIM);
  const __bf16* qwb = (const __bf16*)(ws + WS_QKVW);
  const __bf16* pwb = (const __bf16*)(ws + WS_PROJW);
  const float4* bias4 = (const float4*)(ws + WS_BIAS) + (wv << 10);

  // ---- stage x fragments once per block (wave wv does frags 2wv, 2wv+1) ----
#pragma unroll
  for (int ff = 0; ff < 2; ++ff) {
    const int f = 2 * wv + ff;
    const int mt = f / 3, ks = f - 3 * mt;
    bf16x8 v = cvt8(xw + (16 * mt + l16) * DIM + 32 * ks + 8 * lq);
    *(bf16x8*)(xfrag + (f * 64 + lane) * 8) = v;
  }
  __syncthreads();

#define XV(mt, ks) (*(const bf16x8*)(xfrag + (((mt) * 3 + (ks)) * 64 + lane) * 8))

  // ---- K phase: D = Wk * X^T; D-frag (feat=4lq+r, tok=l16) stays in regs ----
  bf16x4 kb[4];
  {
    const int frow = (HEADS + wv) * 16;
    bf16x8 wb[3];
#pragma unroll
    for (int ks = 0; ks < 3; ++ks) {
      if constexpr (USE_WS)
        wb[ks] = *(const bf16x8*)(qwb + (frow + l16) * 96 + 32 * ks + 8 * lq);
      else
        wb[ks] = cvt8(qkv_w + (frow + l16) * 96 + 32 * ks + 8 * lq);
    }
    const float4 kb4 = *(const float4*)(qkv_b + frow + 4 * lq);
    const float kbv[4] = {kb4.x, kb4.y, kb4.z, kb4.w};
#pragma unroll
    for (int mt = 0; mt < 4; ++mt) {
      f32x4 acc = {0.f, 0.f, 0.f, 0.f};
#pragma unroll
      for (int ks = 0; ks < 3; ++ks) acc = mfma32(wb[ks], XV(mt, ks), acc);
#pragma unroll
      for (int r = 0; r < 4; ++r) kb[mt][r] = (__bf16)(acc[r] + kbv[r]);
    }
  }

  // ---- Q phase: D = Wq * X^T (scaled); registers only ----
  bf16x4 qv4[4];
  {
    const int frow = wv * 16;
    bf16x8 wb[3];
#pragma unroll
    for (int ks = 0; ks < 3; ++ks) {
      if constexpr (USE_WS)
        wb[ks] = *(const bf16x8*)(qwb + (frow + l16) * 96 + 32 * ks + 8 * lq);
      else
        wb[ks] = cvt8(qkv_w + (frow + l16) * 96 + 32 * ks + 8 * lq);
    }
    const float4 qb4 = *(const float4*)(qkv_b + frow + 4 * lq);
    const float qbv[4] = {qb4.x, qb4.y, qb4.z, qb4.w};
#pragma unroll
    for (int mt = 0; mt < 4; ++mt) {
      f32x4 acc = {0.f, 0.f, 0.f, 0.f};
#pragma unroll
      for (int ks = 0; ks < 3; ++ks) acc = mfma32(wb[ks], XV(mt, ks), acc);
#pragma unroll
      for (int r = 0; r < 4; ++r) qv4[mt][r] = (__bf16)((acc[r] + qbv[r]) * 0.25f);
    }
  }

  // ---- V phase: D = X * Wv^T -> vT[feature][token] in LDS ----
  {
    const int frow = (2 * HEADS + wv) * 16;
    bf16x8 wb[3];
#pragma unroll
    for (int ks = 0; ks < 3; ++ks) {
      if constexpr (USE_WS)
        wb[ks] = *(const bf16x8*)(qwb + (frow + l16) * 96 + 32 * ks + 8 * lq);
      else
        wb[ks] = cvt8(qkv_w + (frow + l16) * 96 + 32 * ks + 8 * lq);
    }
    const float vb = qkv_b[frow + l16];
#pragma unroll
    for (int mt = 0; mt < 4; ++mt) {
      f32x4 acc = {0.f, 0.f, 0.f, 0.f};
#pragma unroll
      for (int ks = 0; ks < 3; ++ks) acc = mfma32(XV(mt, ks), wb[ks], acc);
      bf16x4 t;
#pragma unroll
      for (int r = 0; r < 4; ++r) t[r] = (__bf16)(acc[r] + vb);
      *(bf16x4*)(vh + l16 * 72 + 16 * mt + 4 * lq) = t;
    }
  }
  asm volatile("s_waitcnt lgkmcnt(0)" ::: "memory");  // vT visible to all lanes
  bf16x8 vbf[2];
#pragma unroll
  for (int c = 0; c < 2; ++c)
    vbf[c] = *(const bf16x8*)(vh + l16 * 72 + 32 * c + 8 * lq);

  // all waves done with xfrag; vbf reads drained by the barrier's fence
  __syncthreads();

  // ---- attention per q-tile: S^T = K*Q^T (K=16 mfma), bias C-init ----
  // P[q=l16][k] at byte (k>>3)*256 + l16*16 + (k&7)*2  (bijective, 2048 B).
  // Bias prefetched one tile ahead: L2 latency hides under exp/PV.
  f32x4 bn[4];
  if constexpr (USE_WS) {
#pragma unroll
    for (int a = 0; a < 4; ++a) {
      float4 t = bias4[a * 64 + lane];
      bn[a][0] = t.x; bn[a][1] = t.y; bn[a][2] = t.z; bn[a][3] = t.w;
    }
  }

#pragma unroll
  for (int bq = 0; bq < 4; ++bq) {
    f32x4 s[4];
    if constexpr (USE_WS) {
#pragma unroll
      for (int a = 0; a < 4; ++a) s[a] = bn[a];
      if (bq < 3) {
#pragma unroll
        for (int a = 0; a < 4; ++a) {
          float4 t = bias4[((bq + 1) * 4 + a) * 64 + lane];
          bn[a][0] = t.x; bn[a][1] = t.y; bn[a][2] = t.z; bn[a][3] = t.w;
        }
      }
    } else {
#pragma unroll
      for (int a = 0; a < 4; ++a)
#pragma unroll
        for (int r = 0; r < 4; ++r)
          s[a][r] = rpb[rpi[(16 * bq + l16) * 64 + 16 * a + 4 * lq + r] * HEADS + wv];
    }

#pragma unroll
    for (int a = 0; a < 4; ++a) s[a] = mfma16k(kb[a], qv4[bq], s[a]);

    // logits tiny (|s| << 1): exp directly, no max subtraction
    float tp[4];
#pragma unroll
    for (int a = 0; a < 4; ++a) {
      float t0 = 0.f;
#pragma unroll
      for (int r = 0; r < 4; ++r) {
        float e = __expf(s[a][r]);
        s[a][r] = e;
        t0 += e;
      }
      tp[a] = t0;
    }
    float tsum = (tp[0] + tp[1]) + (tp[2] + tp[3]);
    tsum += __shfl_xor(tsum, 16);
    tsum += __shfl_xor(tsum, 32);
    const float rv = 1.0f / tsum;

    // P -> Pt: writer (k=16a+4lq+r) -> bf16 off (2a+(lq>>1))*128+l16*8+(lq&1)*4
#pragma unroll
    for (int a = 0; a < 4; ++a) {
      bf16x4 p;
#pragma unroll
      for (int r = 0; r < 4; ++r) p[r] = (__bf16)(s[a][r] * rv);
      *(bf16x4*)(Pt + (2 * a + (lq >> 1)) * 128 + l16 * 8 + (lq & 1) * 4) = p;
    }
    asm volatile("s_waitcnt lgkmcnt(0)" ::: "memory");

    f32x4 oacc = {0.f, 0.f, 0.f, 0.f};
#pragma unroll
    for (int c = 0; c < 2; ++c) {
      // reader (k=32c+8lq+e) -> bf16 off c*512 + lane*8, linear b128
      const bf16x8 pa = *(const bf16x8*)(Pt + c * 512 + lane * 8);
      oacc = mfma32(pa, vbf[c], oacc);
    }
    asm volatile("s_waitcnt lgkmcnt(0)" ::: "memory");  // drain before overwrite

    // stage this tile's attn-out (ao region valid post-barrier)
#pragma unroll
    for (int r = 0; r < 4; ++r)
      ao[(16 * bq + 4 * lq + r) * 104 + 16 * wv + l16] = (__bf16)oacc[r];
  }
  __syncthreads();

  // ---- proj ----
  bf16x8 wpb[3];
#pragma unroll
  for (int ks = 0; ks < 3; ++ks) {
    if constexpr (USE_WS)
      wpb[ks] = *(const bf16x8*)(pwb + (16 * wv + l16) * 96 + 32 * ks + 8 * lq);
    else
      wpb[ks] = cvt8(proj_w + (16 * wv + l16) * 96 + 32 * ks + 8 * lq);
  }
  const float pb2 = proj_b[16 * wv + l16];
  float* outw = out + (size_t)b * (NTOK * DIM);
#pragma unroll
  for (int mt = 0; mt < 4; ++mt) {
    f32x4 acc = {0.f, 0.f, 0.f, 0.f};
#pragma unroll
    for (int ks = 0; ks < 3; ++ks) {
      bf16x8 aa = *(const bf16x8*)(ao + (16 * mt + l16) * 104 + 32 * ks + 8 * lq);
      acc = mfma32(aa, wpb[ks], acc);
    }
#pragma unroll
    for (int r = 0; r < 4; ++r)
      outw[(16 * mt + 4 * lq + r) * 96 + 16 * wv + l16] = acc[r] + pb2;
  }
}

extern "C" void kernel_launch(void* const* d_in, const int* in_sizes, int n_in,
                              void* d_out, int out_size, void* d_ws, size_t ws_size,
                              hipStream_t stream) {
  const float* x      = (const float*)d_in[0];
  const int*   rpi    = (const int*)d_in[1];
  const float* qkv_w  = (const float*)d_in[2];
  const float* qkv_b  = (const float*)d_in[3];
  const float* proj_w = (const float*)d_in[4];
  const float* proj_b = (const float*)d_in[5];
  const float* rpb    = (const float*)d_in[6];
  float* out = (float*)d_out;

  if (ws_size >= (size_t)WS_TOTAL) {
    prep_kernel<<<240, 256, 0, stream>>>(qkv_w, proj_w, rpb, rpi, (char*)d_ws);
    win_attn<true><<<NWIN, 384, 0, stream>>>(x, rpi, qkv_w, qkv_b, proj_w,
                                             proj_b, rpb, (const char*)d_ws, out);
  } else {
    win_attn<false><<<NWIN, 384, 0, stream>>>(x, rpi, qkv_w, qkv_b, proj_w,
                                              proj_b, rpb, (const char*)d_ws, out);
  }
}